// Round 12
// baseline (477.257 us; speedup 1.0000x reference)
//
#include <hip/hip_runtime.h>
#include <hip/hip_bf16.h>

#define NREL 8
#define NNODE 50000
#define NEDGE 400000
#define DIM 128
#define NCLS 16
#define NBAS 4

#define NBUCK 391      // ceil(50000/128) dst-buckets of 128 nodes
#define CAP 2048       // per-(rel,bucket) capacity in binA (mean 1024, sigma 32)
#define MCAP 10240     // merged per-bucket capacity (mean 8192, sigma 90)
#define CHUNK 8192     // edges per binA block

typedef __attribute__((ext_vector_type(8))) short short8v;
typedef __attribute__((ext_vector_type(4))) float f32x4;

// ---- bf16 helpers ----
__device__ __forceinline__ float bflo(unsigned int p) {
    union { unsigned int i; float f; } c; c.i = p << 16; return c.f;
}
__device__ __forceinline__ float bfhi(unsigned int p) {
    union { unsigned int i; float f; } c; c.i = p & 0xFFFF0000u; return c.f;
}
__device__ __forceinline__ unsigned short f2bf(float f) {
    union { float f; unsigned int i; } c; c.f = f;
    unsigned int r = c.i + 0x7FFFu + ((c.i >> 16) & 1u);
    return (unsigned short)(r >> 16);
}
__device__ __forceinline__ unsigned int pack2bf(float x, float y) {
    return (unsigned int)f2bf(x) | ((unsigned int)f2bf(y) << 16);
}

// edge word: bits[0:16)=src, [16:19)=rel, [19:32)=deg(node,rel)

// ---------------- CSR pass A: bin edges by dst>>7, LDS-staged coalesced writes ----------------

__global__ __launch_bounds__(512) void binA_kernel(
        const int* __restrict__ src, const int* __restrict__ dst,
        int* __restrict__ gcnt, unsigned int* __restrict__ gbuf) {
    __shared__ int cntA[NBUCK];
    __shared__ int exclA[NBUCK];
    __shared__ int gposA[NBUCK];
    __shared__ int arr[512];
    __shared__ unsigned int lbuf[CHUNK];
    int tid = threadIdx.x;
    int r = blockIdx.y;
    int base = blockIdx.x * CHUNK;
    for (int b = tid; b < NBUCK; b += 512) cntA[b] = 0;
    __syncthreads();
    unsigned int vals[16];
    int boffs[16];
    #pragma unroll
    for (int i = 0; i < 16; ++i) {
        int e = base + tid + i * 512;
        vals[i] = 0u; boffs[i] = -1;
        if (e < NEDGE) {
            int d = dst[(size_t)r * NEDGE + e];
            int s = src[(size_t)r * NEDGE + e];
            int b = d >> 7;
            int off = atomicAdd(&cntA[b], 1);
            vals[i] = (unsigned int)s | ((unsigned int)(d & 127) << 16);
            boffs[i] = (b << 13) | off;
        }
    }
    __syncthreads();
    int c = (tid < NBUCK) ? cntA[tid] : 0;
    arr[tid] = c;
    __syncthreads();
    int x = c;
    for (int off = 1; off < 512; off <<= 1) {
        int t = (tid >= off) ? arr[tid - off] : 0;
        __syncthreads();
        x += t; arr[tid] = x;
        __syncthreads();
    }
    if (tid < NBUCK) exclA[tid] = x - c;
    __syncthreads();
    #pragma unroll
    for (int i = 0; i < 16; ++i) {
        if (boffs[i] >= 0) {
            int b = boffs[i] >> 13, off = boffs[i] & 8191;
            lbuf[exclA[b] + off] = vals[i];
        }
    }
    if (tid < NBUCK) gposA[tid] = atomicAdd(&gcnt[r * NBUCK + tid], c);
    __syncthreads();
    int wave = tid >> 6, lane = tid & 63;
    for (int b = wave; b < NBUCK; b += 8) {
        int cb = cntA[b];
        int lb = exclA[b];
        int gp = gposA[b];
        if (gp + cb > CAP) cb = (CAP > gp) ? (CAP - gp) : 0;
        size_t gbo = ((size_t)(r * NBUCK + b)) * CAP + gp;
        for (int i = lane; i < cb; i += 64) gbuf[gbo + i] = lbuf[lb + i];
    }
}

// ---------------- merged bucket scan -> bbase; sentinel rpA[N] ----------------

__global__ __launch_bounds__(512) void merged_scan_kernel(
        const int* __restrict__ gcnt, int* __restrict__ bbase, int* __restrict__ rpA) {
    __shared__ int arr[512];
    int tid = threadIdx.x;
    int c = 0;
    if (tid < NBUCK) {
        #pragma unroll
        for (int r = 0; r < NREL; ++r) {
            int v = gcnt[r * NBUCK + tid];
            c += (v > CAP) ? CAP : v;
        }
        if (c > MCAP) c = MCAP;
    }
    arr[tid] = c;
    __syncthreads();
    int x = c;
    for (int off = 1; off < 512; off <<= 1) {
        int t = (tid >= off) ? arr[tid - off] : 0;
        __syncthreads();
        x += t; arr[tid] = x;
        __syncthreads();
    }
    if (tid < NBUCK) bbase[tid] = x - c;
    if (tid == 511) rpA[NNODE] = x;   // total edges
}

// ---------------- CSR pass B: merged node-major edge list (uint32 words) ----------------

__global__ __launch_bounds__(256) void binB_merged_kernel(
        const int* __restrict__ gcnt, const int* __restrict__ bbase,
        const unsigned int* __restrict__ gbuf,
        int* __restrict__ rpA, unsigned int* __restrict__ ew) {
    int b = blockIdx.x;
    int tid = threadIdx.x;
    __shared__ int deg[1024];     // key = nl*8 + r
    __shared__ int cur[1024];
    __shared__ int arr[256];
    __shared__ unsigned int ebuf[MCAP];   // 40 KB
    for (int k = tid; k < 1024; k += 256) deg[k] = 0;
    __syncthreads();
    int cnts[NREL];
    #pragma unroll
    for (int r = 0; r < NREL; ++r) {
        int v = gcnt[r * NBUCK + b];
        cnts[r] = (v > CAP) ? CAP : v;
    }
    #pragma unroll
    for (int r = 0; r < NREL; ++r) {
        const unsigned int* gb = gbuf + ((size_t)(r * NBUCK + b)) * CAP;
        for (int i = tid; i < cnts[r]; i += 256) {
            int nl = (gb[i] >> 16) & 127;
            atomicAdd(&deg[nl * 8 + r], 1);
        }
    }
    __syncthreads();
    int k0 = tid * 4;
    int s0, s1, s2, s3, tot = 0;
    s0 = tot; tot += deg[k0 + 0];
    s1 = tot; tot += deg[k0 + 1];
    s2 = tot; tot += deg[k0 + 2];
    s3 = tot; tot += deg[k0 + 3];
    arr[tid] = tot;
    __syncthreads();
    int x = tot;
    for (int off = 1; off < 256; off <<= 1) {
        int t = (tid >= off) ? arr[tid - off] : 0;
        __syncthreads();
        x += t; arr[tid] = x;
        __syncthreads();
    }
    int texcl = x - tot;
    cur[k0 + 0] = texcl + s0;
    cur[k0 + 1] = texcl + s1;
    cur[k0 + 2] = texcl + s2;
    cur[k0 + 3] = texcl + s3;
    __syncthreads();
    int base = bbase[b];
    int nodeBase = b * 128;
    if (tid < 128 && nodeBase + tid < NNODE)
        rpA[nodeBase + tid] = base + cur[tid * 8];
    __syncthreads();
    #pragma unroll
    for (int r = 0; r < NREL; ++r) {
        const unsigned int* gb = gbuf + ((size_t)(r * NBUCK + b)) * CAP;
        for (int i = tid; i < cnts[r]; i += 256) {
            unsigned int v = gb[i];
            int nl = (v >> 16) & 127;
            int key = nl * 8 + r;
            int off = atomicAdd(&cur[key], 1);
            if (off < MCAP) {
                unsigned int dg = (unsigned int)deg[key];
                if (dg > 8191u) dg = 8191u;
                ebuf[off] = (v & 0xFFFFu) | ((unsigned int)r << 16) | (dg << 19);
            }
        }
    }
    __syncthreads();
    int total = 0;
    #pragma unroll
    for (int r = 0; r < NREL; ++r) total += cnts[r];
    if (total > MCAP) total = MCAP;
    for (int i = tid; i < total; i += 256) ew[(size_t)base + i] = ebuf[i];
}

// ---------------- embed table fp32 -> bf16 ----------------

__global__ __launch_bounds__(256) void conv_bf16_kernel(
        const float* __restrict__ in, unsigned short* __restrict__ out) {
    size_t i = ((size_t)blockIdx.x * blockDim.x + threadIdx.x) * 4;
    if (i >= (size_t)NREL * NNODE * DIM) return;
    float4 v = *(const float4*)(in + i);
    union { unsigned short us[4]; uint2 u; } pk;
    pk.us[0] = f2bf(v.x); pk.us[1] = f2bf(v.y);
    pk.us[2] = f2bf(v.z); pk.us[3] = f2bf(v.w);
    *(uint2*)(out + i) = pk.u;
}

// ---------------- weight prep ----------------
// w1cT[r][j][k] = sum_b comp[r,b]*w1_basis[b][k][j]  (bf16, transposed for MFMA B)

__global__ void wprep1c_kernel(const float* __restrict__ w1_basis, const float* __restrict__ w1_comp,
                               unsigned short* __restrict__ w1cT) {
    int idx = blockIdx.x * 256 + threadIdx.x;   // 8 * 128 * 128
    if (idx >= NREL * DIM * DIM) return;
    int r = idx >> 14, j = (idx >> 7) & 127, k = idx & 127;
    float s = 0.f;
    #pragma unroll
    for (int b = 0; b < NBAS; ++b)
        s += w1_comp[r * NBAS + b] * w1_basis[(b * DIM + k) * DIM + j];
    w1cT[idx] = f2bf(s);
}

__global__ void wprep2_kernel(const float* __restrict__ w2_basis, const float* __restrict__ w2_comp,
                              unsigned short* __restrict__ w2T) {
    int idx = blockIdx.x * 256 + threadIdx.x;        // 128 cols (r*16+c) x 128 k
    if (idx >= 128 * 128) return;
    int j = idx >> 7, k = idx & 127;
    float s = 0.f;
    #pragma unroll
    for (int b = 0; b < NBAS; ++b)
        s += w2_comp[(j >> 4) * NBAS + b] * w2_basis[(b * DIM + k) * NCLS + (j & 15)];
    w2T[idx] = f2bf(s);
}

// ---------------- Aggregation (quad-packed runs): out = relu(bias + sum_runs (1/dg)*sum_run table[rel][src]) ----------------
// Used for BOTH the embed layer (table=embeds_bf, bias=emb_bias) and layer 1 (table=Y, bias=b1).
// wave = 4 groups of 16 lanes; group g handles edge e+g; lane owns 8 cols.

__global__ __launch_bounds__(256) void agg_relu_kernel(
        const unsigned short* __restrict__ table, const int* __restrict__ rpA,
        const unsigned int* __restrict__ ew, const float* __restrict__ bias,
        unsigned short* __restrict__ out) {
    int wid = (blockIdx.x * blockDim.x + threadIdx.x) >> 6;
    int lane = threadIdx.x & 63;
    if (wid >= NNODE) return;
    int g = lane >> 4, c16 = lane & 15;
    int beg = rpA[wid], end = rpA[wid + 1];
    float a[8] = {0.f, 0.f, 0.f, 0.f, 0.f, 0.f, 0.f, 0.f};
    int e = beg;
    while (e < end) {
        unsigned int q0 = ew[e];
        unsigned int rel = (q0 >> 16) & 7u;
        int dg = (int)(q0 >> 19);
        int re = e + dg; if (re > end) re = end;
        const unsigned short* tab = table + (size_t)rel * NNODE * DIM + c16 * 8;
        float s[8] = {0.f, 0.f, 0.f, 0.f, 0.f, 0.f, 0.f, 0.f};
        int eq = e;
        #pragma unroll 2
        for (; eq + 4 <= re; eq += 4) {
            unsigned int srci = ew[eq + g] & 0xFFFFu;
            uint4 p = *(const uint4*)(tab + (size_t)srci * DIM);
            s[0] += bflo(p.x); s[1] += bfhi(p.x);
            s[2] += bflo(p.y); s[3] += bfhi(p.y);
            s[4] += bflo(p.z); s[5] += bfhi(p.z);
            s[6] += bflo(p.w); s[7] += bfhi(p.w);
        }
        if (eq + g < re) {
            unsigned int srci = ew[eq + g] & 0xFFFFu;
            uint4 p = *(const uint4*)(tab + (size_t)srci * DIM);
            s[0] += bflo(p.x); s[1] += bfhi(p.x);
            s[2] += bflo(p.y); s[3] += bfhi(p.y);
            s[4] += bflo(p.z); s[5] += bfhi(p.z);
            s[6] += bflo(p.w); s[7] += bfhi(p.w);
        }
        float w = 1.0f / (float)dg;   // once per run
        #pragma unroll
        for (int k = 0; k < 8; ++k) a[k] = fmaf(w, s[k], a[k]);
        e = re;
    }
    #pragma unroll
    for (int k = 0; k < 8; ++k) {
        a[k] += __shfl_xor(a[k], 16);
        a[k] += __shfl_xor(a[k], 32);
    }
    if (g == 0) {
        float4 b0 = *(const float4*)(bias + c16 * 8);
        float4 b1v = *(const float4*)(bias + c16 * 8 + 4);
        uint4 o;
        o.x = pack2bf(fmaxf(a[0] + b0.x, 0.f), fmaxf(a[1] + b0.y, 0.f));
        o.y = pack2bf(fmaxf(a[2] + b0.z, 0.f), fmaxf(a[3] + b0.w, 0.f));
        o.z = pack2bf(fmaxf(a[4] + b1v.x, 0.f), fmaxf(a[5] + b1v.y, 0.f));
        o.w = pack2bf(fmaxf(a[6] + b1v.z, 0.f), fmaxf(a[7] + b1v.w, 0.f));
        *(uint4*)(out + (size_t)wid * DIM + c16 * 8) = o;
    }
}

// ---------------- MFMA Y-GEMM: Y[r] = h[M,128]bf16 @ w1cT[r]^T  -> bf16 [8][N][128] ----------------
// Fragment maps (guide m89/m92): A/B lane l: row=l&15, k=(l>>4)*8+j ; D: col=l&15, row=(l>>4)*4+reg.

__global__ __launch_bounds__(256) void ygemm_mfma_kernel(
        const unsigned short* __restrict__ A, const unsigned short* __restrict__ BTall,
        unsigned short* __restrict__ Y, int M) {
    const int K = 128;
    int r = blockIdx.y;
    const unsigned short* BT = BTall + (size_t)r * DIM * K;
    unsigned short* Yr = Y + (size_t)r * NNODE * DIM;
    __shared__ short As[128 * 40];
    __shared__ short Bs[128 * 40];
    int t = threadIdx.x;
    int row0 = blockIdx.x * 128;
    int w = t >> 6, l = t & 63;
    int wrow = w * 32;
    f32x4 acc[2][8];
    f32x4 z4 = {0.f, 0.f, 0.f, 0.f};
    #pragma unroll
    for (int mi = 0; mi < 2; ++mi)
        #pragma unroll
        for (int nj = 0; nj < 8; ++nj) acc[mi][nj] = z4;

    for (int k0 = 0; k0 < K; k0 += 32) {
        #pragma unroll
        for (int i = 0; i < 2; ++i) {
            int chunk = t + i * 256;
            int row = chunk >> 2, kc = chunk & 3;
            int gr = row0 + row;
            short8v v = {0, 0, 0, 0, 0, 0, 0, 0};
            if (gr < M) v = *(const short8v*)(A + (size_t)gr * K + k0 + kc * 8);
            *(short8v*)(&As[row * 40 + kc * 8]) = v;
            short8v u = *(const short8v*)(BT + (size_t)row * K + k0 + kc * 8);
            *(short8v*)(&Bs[row * 40 + kc * 8]) = u;
        }
        __syncthreads();
        short8v a0 = *(const short8v*)(&As[(wrow + (l & 15)) * 40 + (l >> 4) * 8]);
        short8v a1 = *(const short8v*)(&As[(wrow + 16 + (l & 15)) * 40 + (l >> 4) * 8]);
        #pragma unroll
        for (int nj = 0; nj < 8; ++nj) {
            short8v b = *(const short8v*)(&Bs[(nj * 16 + (l & 15)) * 40 + (l >> 4) * 8]);
            acc[0][nj] = __builtin_amdgcn_mfma_f32_16x16x32_bf16(a0, b, acc[0][nj], 0, 0, 0);
            acc[1][nj] = __builtin_amdgcn_mfma_f32_16x16x32_bf16(a1, b, acc[1][nj], 0, 0, 0);
        }
        __syncthreads();
    }
    #pragma unroll
    for (int mi = 0; mi < 2; ++mi) {
        #pragma unroll
        for (int jr = 0; jr < 4; ++jr) {
            int gr = row0 + wrow + mi * 16 + (l >> 4) * 4 + jr;
            if (gr < M) {
                #pragma unroll
                for (int nj = 0; nj < 8; ++nj) {
                    int col = nj * 16 + (l & 15);
                    Yr[(size_t)gr * DIM + col] = f2bf(acc[mi][nj][jr]);
                }
            }
        }
    }
}

// ---------------- MFMA GEMM_T2: T2[r][n][16](bf16) = h1[M,128]bf16 @ w2T^T ----------------

__global__ __launch_bounds__(256) void gemm2_mfma_kernel(
        const unsigned short* __restrict__ A, const unsigned short* __restrict__ BT,
        unsigned short* __restrict__ T2, int M) {
    const int K = 128;
    __shared__ short As[128 * 40];
    __shared__ short Bs[128 * 40];
    int t = threadIdx.x;
    int row0 = blockIdx.x * 128;
    int w = t >> 6, l = t & 63;
    int wrow = w * 32;
    f32x4 acc[2][8];
    f32x4 z4 = {0.f, 0.f, 0.f, 0.f};
    #pragma unroll
    for (int mi = 0; mi < 2; ++mi)
        #pragma unroll
        for (int nj = 0; nj < 8; ++nj) acc[mi][nj] = z4;

    for (int k0 = 0; k0 < K; k0 += 32) {
        #pragma unroll
        for (int i = 0; i < 2; ++i) {
            int chunk = t + i * 256;
            int row = chunk >> 2, kc = chunk & 3;
            int gr = row0 + row;
            short8v v = {0, 0, 0, 0, 0, 0, 0, 0};
            if (gr < M) v = *(const short8v*)(A + (size_t)gr * K + k0 + kc * 8);
            *(short8v*)(&As[row * 40 + kc * 8]) = v;
            short8v u = *(const short8v*)(BT + (size_t)row * K + k0 + kc * 8);
            *(short8v*)(&Bs[row * 40 + kc * 8]) = u;
        }
        __syncthreads();
        short8v a0 = *(const short8v*)(&As[(wrow + (l & 15)) * 40 + (l >> 4) * 8]);
        short8v a1 = *(const short8v*)(&As[(wrow + 16 + (l & 15)) * 40 + (l >> 4) * 8]);
        #pragma unroll
        for (int nj = 0; nj < 8; ++nj) {
            short8v b = *(const short8v*)(&Bs[(nj * 16 + (l & 15)) * 40 + (l >> 4) * 8]);
            acc[0][nj] = __builtin_amdgcn_mfma_f32_16x16x32_bf16(a0, b, acc[0][nj], 0, 0, 0);
            acc[1][nj] = __builtin_amdgcn_mfma_f32_16x16x32_bf16(a1, b, acc[1][nj], 0, 0, 0);
        }
        __syncthreads();
    }
    // col = nj*16 + (l&15): relation = nj, class = l&15
    #pragma unroll
    for (int mi = 0; mi < 2; ++mi) {
        #pragma unroll
        for (int jr = 0; jr < 4; ++jr) {
            int gr = row0 + wrow + mi * 16 + (l >> 4) * 4 + jr;
            if (gr < M) {
                #pragma unroll
                for (int nj = 0; nj < 8; ++nj) {
                    T2[((size_t)nj * NNODE + gr) * NCLS + (l & 15)] = f2bf(acc[mi][nj][jr]);
                }
            }
        }
    }
}

// ---------------- Layer-2 aggregate (flat): out[n][c] = b2[c] + sum_e w_e * T2[rel][src][c] ----------------

__global__ __launch_bounds__(256) void agg2_flat_kernel(
        const unsigned short* __restrict__ T2, const int* __restrict__ rpA,
        const unsigned int* __restrict__ ew, const float* __restrict__ b2,
        float* __restrict__ out) {
    int wid = (blockIdx.x * blockDim.x + threadIdx.x) >> 6;
    int lane = threadIdx.x & 63;
    if (wid >= NNODE) return;
    int q = lane >> 3, il = lane & 7;
    int beg = rpA[wid], end = rpA[wid + 1];
    const unsigned short* tab = T2 + il * 2;
    float sx = 0.f, sy = 0.f;
    for (int e = beg + q; e < end; e += 8) {
        unsigned int qq = ew[e];
        float w = __builtin_amdgcn_rcpf((float)(qq >> 19));   // 1 ulp, fine vs 2.7e-3
        size_t grow = (size_t)(((qq >> 16) & 7u) * NNODE + (qq & 0xFFFFu));
        unsigned int p = *(const unsigned int*)(tab + grow * NCLS);
        sx = fmaf(w, bflo(p), sx);
        sy = fmaf(w, bfhi(p), sy);
    }
    sx += __shfl_xor(sx, 8);  sy += __shfl_xor(sy, 8);
    sx += __shfl_xor(sx, 16); sy += __shfl_xor(sy, 16);
    sx += __shfl_xor(sx, 32); sy += __shfl_xor(sy, 32);
    if (lane < 8) {
        float2 o;
        o.x = sx + b2[il * 2];
        o.y = sy + b2[il * 2 + 1];
        *(float2*)(out + (size_t)wid * NCLS + il * 2) = o;
    }
}

// ---------------- launch ----------------

extern "C" void kernel_launch(void* const* d_in, const int* in_sizes, int n_in,
                              void* d_out, int out_size, void* d_ws, size_t ws_size,
                              hipStream_t stream) {
    const int* edge_src   = (const int*)d_in[0];
    const int* edge_dst   = (const int*)d_in[1];
    const float* embeds   = (const float*)d_in[2];
    const float* emb_bias = (const float*)d_in[3];
    const float* w1_basis = (const float*)d_in[4];
    const float* w1_comp  = (const float*)d_in[5];
    const float* b1       = (const float*)d_in[6];
    const float* w2_basis = (const float*)d_in[7];
    const float* w2_comp  = (const float*)d_in[8];
    const float* b2       = (const float*)d_in[9];
    float* out            = (float*)d_out;

    char* ws = (char*)d_ws;
    size_t off = 0;
    auto take = [&](size_t bytes) {
        char* p = ws + off;
        off += (bytes + 255) & ~(size_t)255;
        return p;
    };
    int* gcnt    = (int*)take((size_t)NREL * NBUCK * 4);
    int* bbase   = (int*)take((size_t)NBUCK * 4);
    int* rpA     = (int*)take((size_t)(NNODE + 1) * 4);
    unsigned int* ewAll = (unsigned int*)take((size_t)NREL * NEDGE * 4);     // 12.8 MB
    unsigned short* h   = (unsigned short*)take((size_t)NNODE * DIM * 2);    // 12.8 MB (h, then h1)
    unsigned short* w1cT = (unsigned short*)take((size_t)NREL * DIM * DIM * 2); // 256 KB
    unsigned short* w2T  = (unsigned short*)take((size_t)128 * 128 * 2);     // 32 KB
    char* big    = take((size_t)NREL * NNODE * DIM * 2);                     // 102.4 MB
    // aliases in big (sequential lifetimes):
    unsigned int* gbuf = (unsigned int*)big;                      // 25.6 MB (CSR build)
    unsigned short* embeds_bf = (unsigned short*)big;             // 102.4 MB (dead after embed agg)
    unsigned short* Y  = (unsigned short*)big;                    // 102.4 MB (layer-1 transformed, dead after agg1)
    unsigned short* T2 = (unsigned short*)(big + (size_t)NNODE * NBAS * DIM * 2);  // 12.8 MB
    unsigned short* h1 = h;                                       // reuse h (dead after ygemm)

    hipMemsetAsync(gcnt, 0, (size_t)NREL * NBUCK * 4, stream);

    binA_kernel<<<dim3((NEDGE + CHUNK - 1) / CHUNK, NREL), 512, 0, stream>>>(
        edge_src, edge_dst, gcnt, gbuf);
    merged_scan_kernel<<<1, 512, 0, stream>>>(gcnt, bbase, rpA);
    binB_merged_kernel<<<NBUCK, 256, 0, stream>>>(gcnt, bbase, gbuf, rpA, ewAll);

    size_t embN = (size_t)NREL * NNODE * DIM;
    conv_bf16_kernel<<<(int)((embN / 4 + 255) / 256), 256, 0, stream>>>(embeds, embeds_bf);
    wprep1c_kernel<<<(NREL * DIM * DIM + 255) / 256, 256, 0, stream>>>(w1_basis, w1_comp, w1cT);
    wprep2_kernel<<<(128 * 128 + 255) / 256, 256, 0, stream>>>(w2_basis, w2_comp, w2T);

    int aggBlocks = (NNODE * 64 + 255) / 256;   // one wave per node
    // embed layer: h = relu(emb_bias + agg(embeds))
    agg_relu_kernel<<<aggBlocks, 256, 0, stream>>>(embeds_bf, rpA, ewAll, emb_bias, h);

    // layer 1 (transform-first): Y[r] = h @ W1comb[r]; h1 = relu(b1 + agg(Y))
    int gemmBlocks = (NNODE + 127) / 128;
    ygemm_mfma_kernel<<<dim3(gemmBlocks, NREL), 256, 0, stream>>>(h, w1cT, Y, NNODE);
    agg_relu_kernel<<<aggBlocks, 256, 0, stream>>>(Y, rpA, ewAll, b1, h1);

    // layer 2 (transform-first): T2 = h1 @ W2all; out = b2 + agg(T2)
    gemm2_mfma_kernel<<<gemmBlocks, 256, 0, stream>>>(h1, w2T, T2, NNODE);
    agg2_flat_kernel<<<aggBlocks, 256, 0, stream>>>(T2, rpA, ewAll, b2, out);
}

// Round 13
// 441.923 us; speedup vs baseline: 1.0800x; 1.0800x over previous
//
#include <hip/hip_runtime.h>
#include <hip/hip_bf16.h>

#define NREL 8
#define NNODE 50000
#define NEDGE 400000
#define DIM 128
#define NCLS 16
#define NBAS 4

#define NBUCK 391      // ceil(50000/128) dst-buckets of 128 nodes
#define CAP 2048       // per-(rel,bucket) capacity in binA
#define MCAP 10240     // merged per-bucket capacity
#define CHUNK 8192     // edges per binA block
#define NCHUNKS 49     // ceil(NEDGE/CHUNK)
#define NBINA (NCHUNKS * NREL)          // 392
#define TOTELEM (51200000)              // NREL*NNODE*DIM
#define SPLITELEM (38400000)            // conv split: [0,38.4M) in K1, rest in K3

typedef __attribute__((ext_vector_type(8))) short short8v;
typedef __attribute__((ext_vector_type(4))) float f32x4;

// ---- bf16 helpers ----
__device__ __forceinline__ float bflo(unsigned int p) {
    union { unsigned int i; float f; } c; c.i = p << 16; return c.f;
}
__device__ __forceinline__ float bfhi(unsigned int p) {
    union { unsigned int i; float f; } c; c.i = p & 0xFFFF0000u; return c.f;
}
__device__ __forceinline__ unsigned short f2bf(float f) {
    union { float f; unsigned int i; } c; c.f = f;
    unsigned int r = c.i + 0x7FFFu + ((c.i >> 16) & 1u);
    return (unsigned short)(r >> 16);
}
__device__ __forceinline__ unsigned int pack2bf(float x, float y) {
    return (unsigned int)f2bf(x) | ((unsigned int)f2bf(y) << 16);
}

// edge word: bits[0:16)=src, [16:19)=rel, [19:32)=deg(node,rel)

// ---------------- K1: binA (blocks 0..391) || conv elems [0,38.4M) (blocks 392..) ----------------

__global__ __launch_bounds__(512) void k1_kernel(
        const int* __restrict__ src, const int* __restrict__ dst,
        int* __restrict__ gcnt, unsigned int* __restrict__ gbuf,
        const float* __restrict__ embeds, unsigned short* __restrict__ embeds_bf) {
    __shared__ int cntA[NBUCK];
    __shared__ int exclA[NBUCK];
    __shared__ int gposA[NBUCK];
    __shared__ int arr[512];
    __shared__ unsigned int lbuf[CHUNK];
    int tid = threadIdx.x;
    int bid = blockIdx.x;
    if (bid >= NBINA) {
        // conv part: 2048 elems per block
        size_t i = (size_t)(bid - NBINA) * 2048 + (size_t)tid * 4;
        float4 v = *(const float4*)(embeds + i);
        union { unsigned short us[4]; uint2 u; } pk;
        pk.us[0] = f2bf(v.x); pk.us[1] = f2bf(v.y);
        pk.us[2] = f2bf(v.z); pk.us[3] = f2bf(v.w);
        *(uint2*)(embeds_bf + i) = pk.u;
        return;
    }
    int r = bid / NCHUNKS;
    int base = (bid % NCHUNKS) * CHUNK;
    for (int b = tid; b < NBUCK; b += 512) cntA[b] = 0;
    __syncthreads();
    unsigned int vals[16];
    int boffs[16];
    #pragma unroll
    for (int i = 0; i < 16; ++i) {
        int e = base + tid + i * 512;
        vals[i] = 0u; boffs[i] = -1;
        if (e < NEDGE) {
            int d = dst[(size_t)r * NEDGE + e];
            int s = src[(size_t)r * NEDGE + e];
            int b = d >> 7;
            int off = atomicAdd(&cntA[b], 1);
            vals[i] = (unsigned int)s | ((unsigned int)(d & 127) << 16);
            boffs[i] = (b << 13) | off;
        }
    }
    __syncthreads();
    int c = (tid < NBUCK) ? cntA[tid] : 0;
    arr[tid] = c;
    __syncthreads();
    int x = c;
    for (int off = 1; off < 512; off <<= 1) {
        int t = (tid >= off) ? arr[tid - off] : 0;
        __syncthreads();
        x += t; arr[tid] = x;
        __syncthreads();
    }
    if (tid < NBUCK) exclA[tid] = x - c;
    __syncthreads();
    #pragma unroll
    for (int i = 0; i < 16; ++i) {
        if (boffs[i] >= 0) {
            int b = boffs[i] >> 13, off = boffs[i] & 8191;
            lbuf[exclA[b] + off] = vals[i];
        }
    }
    if (tid < NBUCK) gposA[tid] = atomicAdd(&gcnt[r * NBUCK + tid], c);
    __syncthreads();
    int wave = tid >> 6, lane = tid & 63;
    for (int b = wave; b < NBUCK; b += 8) {
        int cb = cntA[b];
        int lb = exclA[b];
        int gp = gposA[b];
        if (gp + cb > CAP) cb = (CAP > gp) ? (CAP - gp) : 0;
        size_t gbo = ((size_t)(r * NBUCK + b)) * CAP + gp;
        for (int i = lane; i < cb; i += 64) gbuf[gbo + i] = lbuf[lb + i];
    }
}

// ---------------- merged bucket scan -> bbase; sentinel rpA[N] ----------------

__global__ __launch_bounds__(512) void merged_scan_kernel(
        const int* __restrict__ gcnt, int* __restrict__ bbase, int* __restrict__ rpA) {
    __shared__ int arr[512];
    int tid = threadIdx.x;
    int c = 0;
    if (tid < NBUCK) {
        #pragma unroll
        for (int r = 0; r < NREL; ++r) {
            int v = gcnt[r * NBUCK + tid];
            c += (v > CAP) ? CAP : v;
        }
        if (c > MCAP) c = MCAP;
    }
    arr[tid] = c;
    __syncthreads();
    int x = c;
    for (int off = 1; off < 512; off <<= 1) {
        int t = (tid >= off) ? arr[tid - off] : 0;
        __syncthreads();
        x += t; arr[tid] = x;
        __syncthreads();
    }
    if (tid < NBUCK) bbase[tid] = x - c;
    if (tid == 511) rpA[NNODE] = x;   // total edges
}

// ---------------- K2: binB (blocks 0..390) || wprep1 (391..646) || wprep2 (647..710) ----------------

__global__ __launch_bounds__(256) void k2_kernel(
        const int* __restrict__ gcnt, const int* __restrict__ bbase,
        const unsigned int* __restrict__ gbuf,
        int* __restrict__ rpA, unsigned int* __restrict__ ew,
        const float* __restrict__ w1_basis, unsigned short* __restrict__ w1T,
        const float* __restrict__ w2_basis, const float* __restrict__ w2_comp,
        unsigned short* __restrict__ w2T) {
    __shared__ int deg[1024];     // key = nl*8 + r
    __shared__ int cur[1024];
    __shared__ int arr[256];
    __shared__ unsigned int ebuf[MCAP];   // 40 KB
    int tid = threadIdx.x;
    int bid = blockIdx.x;
    if (bid >= NBUCK) {
        if (bid < NBUCK + 256) {
            int idx = (bid - NBUCK) * 256 + tid;       // 128 cols x 512 k
            int j = idx >> 9, k = idx & 511;
            w1T[idx] = f2bf(w1_basis[k * 128 + j]);
        } else {
            int idx = (bid - NBUCK - 256) * 256 + tid; // 128 cols (r*16+c) x 128 k
            int j = idx >> 7, k = idx & 127;
            float s = 0.f;
            #pragma unroll
            for (int b = 0; b < NBAS; ++b)
                s += w2_comp[(j >> 4) * NBAS + b] * w2_basis[(b * DIM + k) * NCLS + (j & 15)];
            w2T[idx] = f2bf(s);
        }
        return;
    }
    int b = bid;
    for (int k = tid; k < 1024; k += 256) deg[k] = 0;
    __syncthreads();
    int cnts[NREL];
    #pragma unroll
    for (int r = 0; r < NREL; ++r) {
        int v = gcnt[r * NBUCK + b];
        cnts[r] = (v > CAP) ? CAP : v;
    }
    #pragma unroll
    for (int r = 0; r < NREL; ++r) {
        const unsigned int* gb = gbuf + ((size_t)(r * NBUCK + b)) * CAP;
        for (int i = tid; i < cnts[r]; i += 256) {
            int nl = (gb[i] >> 16) & 127;
            atomicAdd(&deg[nl * 8 + r], 1);
        }
    }
    __syncthreads();
    int k0 = tid * 4;
    int s0, s1, s2, s3, tot = 0;
    s0 = tot; tot += deg[k0 + 0];
    s1 = tot; tot += deg[k0 + 1];
    s2 = tot; tot += deg[k0 + 2];
    s3 = tot; tot += deg[k0 + 3];
    arr[tid] = tot;
    __syncthreads();
    int x = tot;
    for (int off = 1; off < 256; off <<= 1) {
        int t = (tid >= off) ? arr[tid - off] : 0;
        __syncthreads();
        x += t; arr[tid] = x;
        __syncthreads();
    }
    int texcl = x - tot;
    cur[k0 + 0] = texcl + s0;
    cur[k0 + 1] = texcl + s1;
    cur[k0 + 2] = texcl + s2;
    cur[k0 + 3] = texcl + s3;
    __syncthreads();
    int base = bbase[b];
    int nodeBase = b * 128;
    if (tid < 128 && nodeBase + tid < NNODE)
        rpA[nodeBase + tid] = base + cur[tid * 8];
    __syncthreads();
    #pragma unroll
    for (int r = 0; r < NREL; ++r) {
        const unsigned int* gb = gbuf + ((size_t)(r * NBUCK + b)) * CAP;
        for (int i = tid; i < cnts[r]; i += 256) {
            unsigned int v = gb[i];
            int nl = (v >> 16) & 127;
            int key = nl * 8 + r;
            int off = atomicAdd(&cur[key], 1);
            if (off < MCAP) {
                unsigned int dg = (unsigned int)deg[key];
                if (dg > 8191u) dg = 8191u;
                ebuf[off] = (v & 0xFFFFu) | ((unsigned int)r << 16) | (dg << 19);
            }
        }
    }
    __syncthreads();
    int total = 0;
    #pragma unroll
    for (int r = 0; r < NREL; ++r) total += cnts[r];
    if (total > MCAP) total = MCAP;
    for (int i = tid; i < total; i += 256) ew[(size_t)base + i] = ebuf[i];
}

// ---------------- K3: conv tail elems [38.4M, 51.2M) ----------------

__global__ __launch_bounds__(256) void k3_conv_kernel(
        const float* __restrict__ in, unsigned short* __restrict__ out) {
    size_t i = (size_t)SPLITELEM + (size_t)blockIdx.x * 1024 + (size_t)threadIdx.x * 4;
    float4 v = *(const float4*)(in + i);
    union { unsigned short us[4]; uint2 u; } pk;
    pk.us[0] = f2bf(v.x); pk.us[1] = f2bf(v.y);
    pk.us[2] = f2bf(v.z); pk.us[3] = f2bf(v.w);
    *(uint2*)(out + i) = pk.u;
}

// ---------------- Embed aggregation (quad-packed runs): h = relu(bias + sum_runs (1/dg)*sum_run tab[rel][src]) ----------------

__global__ __launch_bounds__(256) void agg_relu_kernel(
        const unsigned short* __restrict__ table, const int* __restrict__ rpA,
        const unsigned int* __restrict__ ew, const float* __restrict__ bias,
        unsigned short* __restrict__ out) {
    int wid = (blockIdx.x * blockDim.x + threadIdx.x) >> 6;
    int lane = threadIdx.x & 63;
    if (wid >= NNODE) return;
    int g = lane >> 4, c16 = lane & 15;
    int beg = rpA[wid], end = rpA[wid + 1];
    float a[8] = {0.f, 0.f, 0.f, 0.f, 0.f, 0.f, 0.f, 0.f};
    int e = beg;
    while (e < end) {
        unsigned int q0 = ew[e];
        unsigned int rel = (q0 >> 16) & 7u;
        int dg = (int)(q0 >> 19);
        int re = e + dg; if (re > end) re = end;
        const unsigned short* tab = table + (size_t)rel * NNODE * DIM + c16 * 8;
        float s[8] = {0.f, 0.f, 0.f, 0.f, 0.f, 0.f, 0.f, 0.f};
        int eq = e;
        #pragma unroll 2
        for (; eq + 4 <= re; eq += 4) {
            unsigned int srci = ew[eq + g] & 0xFFFFu;
            uint4 p = *(const uint4*)(tab + (size_t)srci * DIM);
            s[0] += bflo(p.x); s[1] += bfhi(p.x);
            s[2] += bflo(p.y); s[3] += bfhi(p.y);
            s[4] += bflo(p.z); s[5] += bfhi(p.z);
            s[6] += bflo(p.w); s[7] += bfhi(p.w);
        }
        if (eq + g < re) {
            unsigned int srci = ew[eq + g] & 0xFFFFu;
            uint4 p = *(const uint4*)(tab + (size_t)srci * DIM);
            s[0] += bflo(p.x); s[1] += bfhi(p.x);
            s[2] += bflo(p.y); s[3] += bfhi(p.y);
            s[4] += bflo(p.z); s[5] += bfhi(p.z);
            s[6] += bflo(p.w); s[7] += bfhi(p.w);
        }
        float w = 1.0f / (float)dg;   // once per run
        #pragma unroll
        for (int k = 0; k < 8; ++k) a[k] = fmaf(w, s[k], a[k]);
        e = re;
    }
    #pragma unroll
    for (int k = 0; k < 8; ++k) {
        a[k] += __shfl_xor(a[k], 16);
        a[k] += __shfl_xor(a[k], 32);
    }
    if (g == 0) {
        float4 b0 = *(const float4*)(bias + c16 * 8);
        float4 b1v = *(const float4*)(bias + c16 * 8 + 4);
        uint4 o;
        o.x = pack2bf(fmaxf(a[0] + b0.x, 0.f), fmaxf(a[1] + b0.y, 0.f));
        o.y = pack2bf(fmaxf(a[2] + b0.z, 0.f), fmaxf(a[3] + b0.w, 0.f));
        o.z = pack2bf(fmaxf(a[4] + b1v.x, 0.f), fmaxf(a[5] + b1v.y, 0.f));
        o.w = pack2bf(fmaxf(a[6] + b1v.z, 0.f), fmaxf(a[7] + b1v.w, 0.f));
        *(uint4*)(out + (size_t)wid * DIM + c16 * 8) = o;
    }
}

// ---------------- Layer-1 aggregate+combine (quad-packed runs, r11-proven) ----------------
// h table is node-only (row = src). Per-run sum, basis-combine at flush, combine groups at end.

__global__ __launch_bounds__(256) void agg1_flat_kernel(
        const unsigned short* __restrict__ feat, const int* __restrict__ rpA,
        const unsigned int* __restrict__ ew, const float* __restrict__ comp,
        unsigned short* __restrict__ z) {
    __shared__ float compS[32];
    if (threadIdx.x < 32) compS[threadIdx.x] = comp[threadIdx.x];
    __syncthreads();
    int wid = (blockIdx.x * blockDim.x + threadIdx.x) >> 6;
    int lane = threadIdx.x & 63;
    if (wid >= NNODE) return;
    int g = lane >> 4, c16 = lane & 15;
    int beg = rpA[wid], end = rpA[wid + 1];
    const unsigned short* tab = feat + c16 * 8;
    float a[4][8];
    #pragma unroll
    for (int b = 0; b < 4; ++b)
        #pragma unroll
        for (int k = 0; k < 8; ++k) a[b][k] = 0.f;
    int e = beg;
    while (e < end) {
        unsigned int q0 = ew[e];
        unsigned int rel = (q0 >> 16) & 7u;
        int dg = (int)(q0 >> 19);
        int re = e + dg; if (re > end) re = end;
        float s[8] = {0.f, 0.f, 0.f, 0.f, 0.f, 0.f, 0.f, 0.f};
        int eq = e;
        #pragma unroll 2
        for (; eq + 4 <= re; eq += 4) {
            unsigned int srci = ew[eq + g] & 0xFFFFu;
            uint4 p = *(const uint4*)(tab + (size_t)srci * DIM);
            s[0] += bflo(p.x); s[1] += bfhi(p.x);
            s[2] += bflo(p.y); s[3] += bfhi(p.y);
            s[4] += bflo(p.z); s[5] += bfhi(p.z);
            s[6] += bflo(p.w); s[7] += bfhi(p.w);
        }
        if (eq + g < re) {
            unsigned int srci = ew[eq + g] & 0xFFFFu;
            uint4 p = *(const uint4*)(tab + (size_t)srci * DIM);
            s[0] += bflo(p.x); s[1] += bfhi(p.x);
            s[2] += bflo(p.y); s[3] += bfhi(p.y);
            s[4] += bflo(p.z); s[5] += bfhi(p.z);
            s[6] += bflo(p.w); s[7] += bfhi(p.w);
        }
        float w = 1.0f / (float)dg;   // once per run
        unsigned int r4 = rel << 2;
        float w0 = w * compS[r4], w1 = w * compS[r4 + 1];
        float w2 = w * compS[r4 + 2], w3 = w * compS[r4 + 3];
        #pragma unroll
        for (int k = 0; k < 8; ++k) {
            a[0][k] = fmaf(w0, s[k], a[0][k]);
            a[1][k] = fmaf(w1, s[k], a[1][k]);
            a[2][k] = fmaf(w2, s[k], a[2][k]);
            a[3][k] = fmaf(w3, s[k], a[3][k]);
        }
        e = re;
    }
    #pragma unroll
    for (int b = 0; b < 4; ++b)
        #pragma unroll
        for (int k = 0; k < 8; ++k) {
            a[b][k] += __shfl_xor(a[b][k], 16);
            a[b][k] += __shfl_xor(a[b][k], 32);
        }
    if (g == 0) {
        unsigned short* zp = z + (size_t)wid * (NBAS * DIM) + c16 * 8;
        #pragma unroll
        for (int b = 0; b < 4; ++b) {
            uint4 o;
            o.x = pack2bf(a[b][0], a[b][1]);
            o.y = pack2bf(a[b][2], a[b][3]);
            o.z = pack2bf(a[b][4], a[b][5]);
            o.w = pack2bf(a[b][6], a[b][7]);
            *(uint4*)(zp + b * 128) = o;
        }
    }
}

// ---------------- MFMA GEMM1: h1 = relu(Z[M,512]bf16 @ w1T^T + b1) -> bf16 [M,128] (r10/r11-proven) ----------------

__global__ __launch_bounds__(256) void gemm1_mfma_kernel(
        const unsigned short* __restrict__ A, const unsigned short* __restrict__ BT,
        const float* __restrict__ bias, unsigned short* __restrict__ C, int M) {
    const int K = 512;
    __shared__ short As[128 * 40];
    __shared__ short Bs[128 * 40];
    int t = threadIdx.x;
    int row0 = blockIdx.x * 128;
    int w = t >> 6, l = t & 63;
    int wrow = w * 32;
    f32x4 acc[2][8];
    f32x4 z4 = {0.f, 0.f, 0.f, 0.f};
    #pragma unroll
    for (int mi = 0; mi < 2; ++mi)
        #pragma unroll
        for (int nj = 0; nj < 8; ++nj) acc[mi][nj] = z4;

    for (int k0 = 0; k0 < K; k0 += 32) {
        #pragma unroll
        for (int i = 0; i < 2; ++i) {
            int chunk = t + i * 256;
            int row = chunk >> 2, kc = chunk & 3;
            int gr = row0 + row;
            short8v v = {0, 0, 0, 0, 0, 0, 0, 0};
            if (gr < M) v = *(const short8v*)(A + (size_t)gr * K + k0 + kc * 8);
            *(short8v*)(&As[row * 40 + kc * 8]) = v;
            short8v u = *(const short8v*)(BT + (size_t)row * K + k0 + kc * 8);
            *(short8v*)(&Bs[row * 40 + kc * 8]) = u;
        }
        __syncthreads();
        short8v a0 = *(const short8v*)(&As[(wrow + (l & 15)) * 40 + (l >> 4) * 8]);
        short8v a1 = *(const short8v*)(&As[(wrow + 16 + (l & 15)) * 40 + (l >> 4) * 8]);
        #pragma unroll
        for (int nj = 0; nj < 8; ++nj) {
            short8v b = *(const short8v*)(&Bs[(nj * 16 + (l & 15)) * 40 + (l >> 4) * 8]);
            acc[0][nj] = __builtin_amdgcn_mfma_f32_16x16x32_bf16(a0, b, acc[0][nj], 0, 0, 0);
            acc[1][nj] = __builtin_amdgcn_mfma_f32_16x16x32_bf16(a1, b, acc[1][nj], 0, 0, 0);
        }
        __syncthreads();
    }
    #pragma unroll
    for (int mi = 0; mi < 2; ++mi) {
        #pragma unroll
        for (int jr = 0; jr < 4; ++jr) {
            int gr = row0 + wrow + mi * 16 + (l >> 4) * 4 + jr;
            if (gr < M) {
                #pragma unroll
                for (int nj = 0; nj < 8; ++nj) {
                    int col = nj * 16 + (l & 15);
                    float v = acc[mi][nj][jr] + bias[col];
                    C[(size_t)gr * 128 + col] = f2bf(fmaxf(v, 0.f));
                }
            }
        }
    }
}

// ---------------- MFMA GEMM_T2: T2[r][n][16](bf16) = h1[M,128]bf16 @ w2T^T ----------------

__global__ __launch_bounds__(256) void gemm2_mfma_kernel(
        const unsigned short* __restrict__ A, const unsigned short* __restrict__ BT,
        unsigned short* __restrict__ T2, int M) {
    const int K = 128;
    __shared__ short As[128 * 40];
    __shared__ short Bs[128 * 40];
    int t = threadIdx.x;
    int row0 = blockIdx.x * 128;
    int w = t >> 6, l = t & 63;
    int wrow = w * 32;
    f32x4 acc[2][8];
    f32x4 z4 = {0.f, 0.f, 0.f, 0.f};
    #pragma unroll
    for (int mi = 0; mi < 2; ++mi)
        #pragma unroll
        for (int nj = 0; nj < 8; ++nj) acc[mi][nj] = z4;

    for (int k0 = 0; k0 < K; k0 += 32) {
        #pragma unroll
        for (int i = 0; i < 2; ++i) {
            int chunk = t + i * 256;
            int row = chunk >> 2, kc = chunk & 3;
            int gr = row0 + row;
            short8v v = {0, 0, 0, 0, 0, 0, 0, 0};
            if (gr < M) v = *(const short8v*)(A + (size_t)gr * K + k0 + kc * 8);
            *(short8v*)(&As[row * 40 + kc * 8]) = v;
            short8v u = *(const short8v*)(BT + (size_t)row * K + k0 + kc * 8);
            *(short8v*)(&Bs[row * 40 + kc * 8]) = u;
        }
        __syncthreads();
        short8v a0 = *(const short8v*)(&As[(wrow + (l & 15)) * 40 + (l >> 4) * 8]);
        short8v a1 = *(const short8v*)(&As[(wrow + 16 + (l & 15)) * 40 + (l >> 4) * 8]);
        #pragma unroll
        for (int nj = 0; nj < 8; ++nj) {
            short8v b = *(const short8v*)(&Bs[(nj * 16 + (l & 15)) * 40 + (l >> 4) * 8]);
            acc[0][nj] = __builtin_amdgcn_mfma_f32_16x16x32_bf16(a0, b, acc[0][nj], 0, 0, 0);
            acc[1][nj] = __builtin_amdgcn_mfma_f32_16x16x32_bf16(a1, b, acc[1][nj], 0, 0, 0);
        }
        __syncthreads();
    }
    // col = nj*16 + (l&15): relation = nj, class = l&15
    #pragma unroll
    for (int mi = 0; mi < 2; ++mi) {
        #pragma unroll
        for (int jr = 0; jr < 4; ++jr) {
            int gr = row0 + wrow + mi * 16 + (l >> 4) * 4 + jr;
            if (gr < M) {
                #pragma unroll
                for (int nj = 0; nj < 8; ++nj) {
                    T2[((size_t)nj * NNODE + gr) * NCLS + (l & 15)] = f2bf(acc[mi][nj][jr]);
                }
            }
        }
    }
}

// ---------------- Layer-2 aggregate (flat): out[n][c] = b2[c] + sum_e w_e * T2[rel][src][c] ----------------

__global__ __launch_bounds__(256) void agg2_flat_kernel(
        const unsigned short* __restrict__ T2, const int* __restrict__ rpA,
        const unsigned int* __restrict__ ew, const float* __restrict__ b2,
        float* __restrict__ out) {
    int wid = (blockIdx.x * blockDim.x + threadIdx.x) >> 6;
    int lane = threadIdx.x & 63;
    if (wid >= NNODE) return;
    int q = lane >> 3, il = lane & 7;
    int beg = rpA[wid], end = rpA[wid + 1];
    const unsigned short* tab = T2 + il * 2;
    float sx = 0.f, sy = 0.f;
    for (int e = beg + q; e < end; e += 8) {
        unsigned int qq = ew[e];
        float w = __builtin_amdgcn_rcpf((float)(qq >> 19));   // 1 ulp, fine vs 2.7e-3
        size_t grow = (size_t)(((qq >> 16) & 7u) * NNODE + (qq & 0xFFFFu));
        unsigned int p = *(const unsigned int*)(tab + grow * NCLS);
        sx = fmaf(w, bflo(p), sx);
        sy = fmaf(w, bfhi(p), sy);
    }
    sx += __shfl_xor(sx, 8);  sy += __shfl_xor(sy, 8);
    sx += __shfl_xor(sx, 16); sy += __shfl_xor(sy, 16);
    sx += __shfl_xor(sx, 32); sy += __shfl_xor(sy, 32);
    if (lane < 8) {
        float2 o;
        o.x = sx + b2[il * 2];
        o.y = sy + b2[il * 2 + 1];
        *(float2*)(out + (size_t)wid * NCLS + il * 2) = o;
    }
}

// ---------------- launch ----------------

extern "C" void kernel_launch(void* const* d_in, const int* in_sizes, int n_in,
                              void* d_out, int out_size, void* d_ws, size_t ws_size,
                              hipStream_t stream) {
    const int* edge_src   = (const int*)d_in[0];
    const int* edge_dst   = (const int*)d_in[1];
    const float* embeds   = (const float*)d_in[2];
    const float* emb_bias = (const float*)d_in[3];
    const float* w1_basis = (const float*)d_in[4];
    const float* w1_comp  = (const float*)d_in[5];
    const float* b1       = (const float*)d_in[6];
    const float* w2_basis = (const float*)d_in[7];
    const float* w2_comp  = (const float*)d_in[8];
    const float* b2       = (const float*)d_in[9];
    float* out            = (float*)d_out;

    char* ws = (char*)d_ws;
    size_t off = 0;
    auto take = [&](size_t bytes) {
        char* p = ws + off;
        off += (bytes + 255) & ~(size_t)255;
        return p;
    };
    int* gcnt    = (int*)take((size_t)NREL * NBUCK * 4);
    int* bbase   = (int*)take((size_t)NBUCK * 4);
    int* rpA     = (int*)take((size_t)(NNODE + 1) * 4);
    unsigned int* ewAll = (unsigned int*)take((size_t)NREL * NEDGE * 4);    // 12.8 MB
    unsigned short* h   = (unsigned short*)take((size_t)NNODE * DIM * 2);   // 12.8 MB
    unsigned short* w1T = (unsigned short*)take((size_t)128 * 512 * 2);     // 128 KB
    unsigned short* w2T = (unsigned short*)take((size_t)128 * 128 * 2);     // 32 KB
    char* big    = take((size_t)NREL * NNODE * DIM * 2);                    // 102.4 MB
    // aliases in big:
    //   embeds_bf [0, 102.4 MB)            — written K1 ([0,76.8)) + K3 ([76.8,102.4)); dead after embed agg
    //   gbuf      [76.8, 102.4 MB)         — written by binA (K1), read by binB (K2), dead before K3
    //   z         [0, 51.2 MB)             — layer-1 agg output
    //   T2        [51.2, 64 MB)            — layer-2 transformed
    //   h1        [64, 76.8 MB)            — layer-1 output
    unsigned short* embeds_bf = (unsigned short*)big;
    unsigned int* gbuf = (unsigned int*)(big + (size_t)SPLITELEM * 2);      // = big + 76.8 MB
    unsigned short* z  = (unsigned short*)big;
    unsigned short* T2 = (unsigned short*)(big + (size_t)NNODE * NBAS * DIM * 2);
    unsigned short* h1 = (unsigned short*)(big + (size_t)NNODE * NBAS * DIM * 2 + (size_t)NREL * NNODE * NCLS * 2);

    hipMemsetAsync(gcnt, 0, (size_t)NREL * NBUCK * 4, stream);

    // K1: binA (392 blocks) || conv elems [0, 38.4M) (18750 blocks)
    k1_kernel<<<NBINA + 18750, 512, 0, stream>>>(edge_src, edge_dst, gcnt, gbuf,
                                                 embeds, embeds_bf);
    merged_scan_kernel<<<1, 512, 0, stream>>>(gcnt, bbase, rpA);
    // K2: binB (391) || wprep1 (256) || wprep2 (64)
    k2_kernel<<<NBUCK + 256 + 64, 256, 0, stream>>>(gcnt, bbase, gbuf, rpA, ewAll,
                                                    w1_basis, w1T, w2_basis, w2_comp, w2T);
    // K3: conv tail [38.4M, 51.2M)  (gbuf dead now)
    k3_conv_kernel<<<12500, 256, 0, stream>>>(embeds, embeds_bf);

    int aggBlocks = (NNODE * 64 + 255) / 256;   // one wave per node
    agg_relu_kernel<<<aggBlocks, 256, 0, stream>>>(embeds_bf, rpA, ewAll, emb_bias, h);

    agg1_flat_kernel<<<aggBlocks, 256, 0, stream>>>(h, rpA, ewAll, w1_comp, z);
    int gemmBlocks = (NNODE + 127) / 128;
    gemm1_mfma_kernel<<<gemmBlocks, 256, 0, stream>>>(z, w1T, b1, h1, NNODE);

    gemm2_mfma_kernel<<<gemmBlocks, 256, 0, stream>>>(h1, w2T, T2, NNODE);
    agg2_flat_kernel<<<aggBlocks, 256, 0, stream>>>(T2, rpA, ewAll, b2, out);
}